// Round 4
// baseline (5267.030 us; speedup 1.0000x reference)
//
#include <hip/hip_runtime.h>
#include <math.h>

#define T 64
#define H 256

typedef _Float16 f16;
typedef _Float16 f16x8 __attribute__((ext_vector_type(8)));
typedef float f32x4 __attribute__((ext_vector_type(4)));

__device__ __forceinline__ float sigm(float x) { return 1.f / (1.f + __expf(-x)); }
__device__ __forceinline__ float ftanh(float x) { return 1.f - 2.f / (__expf(2.f * x) + 1.f); }

// grid barrier: monotonic counter, release add + acquire spin (agent scope).
__device__ __forceinline__ void gridbar(unsigned* bar, unsigned target) {
  __threadfence();
  __syncthreads();
  if (threadIdx.x == 0) {
    __hip_atomic_fetch_add(bar, 1u, __ATOMIC_ACQ_REL, __HIP_MEMORY_SCOPE_AGENT);
    while (__hip_atomic_load(bar, __ATOMIC_ACQUIRE, __HIP_MEMORY_SCOPE_AGENT) < target)
      __builtin_amdgcn_s_sleep(1);
    __threadfence();
  }
  __syncthreads();
}

// ---------------------------------------------------------------------------
// k_prep_u: coalesced frag-ordering of the 65 scan-LSTM U matrices into f16.
// Read layout per fragment read in k_scan:
//   Uf2 flat idx = ((((lstm*8 + w)*8 + kt)*8 + ct)*64 + l)*8 + e
//   = U[k = kt*32 + (l>>4)*8 + e][col = g*256 + w*32 + nt*16 + (l&15)]
//   with g = ct>>1, nt = ct&1.
// One block per (lstm, kt): stage 32 rows x 1024 cols in LDS, emit coalesced.
// ---------------------------------------------------------------------------
__global__ __launch_bounds__(256) void k_prep_u(
    const float* __restrict__ Uxp, const float* __restrict__ Uxn,
    const float* __restrict__ Uy, f16* __restrict__ Uf2)
{
  __shared__ f16 lds[32][1024];  // 64 KB
  const int tid = threadIdx.x;
  const int lstm = blockIdx.x >> 3, kt = blockIdx.x & 7;
  const float* src = (lstm < 32) ? (Uxp + (size_t)lstm * 262144)
                   : (lstm < 64) ? (Uxn + (size_t)(lstm - 32) * 262144)
                   : Uy;
  const int k0 = kt * 32;
  for (int i = tid; i < 32 * 1024; i += 256) {
    const int row = i >> 10, col = i & 1023;
    lds[row][col] = (f16)src[(size_t)(k0 + row) * 1024 + col];
  }
  __syncthreads();
  const int l = tid & 63, c0 = tid >> 6;
  for (int c = c0; c < 64; c += 4) {
    const int w = c >> 3, ct = c & 7, g = ct >> 1, nt = ct & 1;
    f16x8 v;
    #pragma unroll
    for (int e = 0; e < 8; ++e)
      v[e] = lds[(l >> 4) * 8 + e][g * 256 + w * 32 + nt * 16 + (l & 15)];
    *(f16x8*)(Uf2 + (((((size_t)lstm * 8 + w) * 8 + kt) * 8 + ct) * 64 + l) * 8) = v;
  }
}

// ---------------------------------------------------------------------------
// k_prep_umi: B-fragments for the MI-LSTM (slot 0-3 Um gates, 4-5 Upa,
// 6-7 Una, 8 Wa), per (blk 0..15, slot) a 16-col ntile.
// ---------------------------------------------------------------------------
__global__ __launch_bounds__(512) void k_prep_umi(
    const float* __restrict__ Um, const float* __restrict__ Upa,
    const float* __restrict__ Una, const float* __restrict__ Wa,
    f16* __restrict__ Ufmi)
{
  const int blk = blockIdx.x / 9, slot = blockIdx.x % 9;
  const int kt = threadIdx.x >> 6, l = threadIdx.x & 63;
  const int n = blk * 16 + (l & 15);
  const int k0 = kt * 32 + (l >> 4) * 8;
  const float* src; int col, ld;
  if (slot < 4)      { src = Um;  col = slot * 256 + n;       ld = 1024; }
  else if (slot < 6) { src = Upa; col = (slot - 4) * 256 + n; ld = 512;  }
  else if (slot < 8) { src = Una; col = (slot - 6) * 256 + n; ld = 512;  }
  else               { src = Wa;  col = n;                    ld = 256;  }
  f16x8 v;
  #pragma unroll
  for (int e = 0; e < 8; ++e) v[e] = (f16)src[(size_t)(k0 + e) * ld + col];
  *(f16x8*)(Ufmi + (((size_t)blk * 9 + slot) * 8 + kt) * 512 + (size_t)l * 8) = v;
}

// ---------------------------------------------------------------------------
// k_prep_x: X[b][t][f] -> Xt[s][f][t][b]
// ---------------------------------------------------------------------------
__global__ __launch_bounds__(512) void k_prep_x(
    const float* __restrict__ Xp, const float* __restrict__ Xn, float* __restrict__ Xt)
{
  const int s = blockIdx.x >> 5, f = blockIdx.x & 31;
  const float* X = s ? Xn : Xp;
  for (int i = threadIdx.x; i < 2048; i += 512) {
    const int t = i >> 5, b = i & 31;
    Xt[((size_t)(s * 32 + f) * 64 + t) * 32 + b] = X[((size_t)b * 64 + t) * 32 + f];
  }
}

// ---------------------------------------------------------------------------
// k_prep_yg0: yg0t[t][col][b] = Y[b,t,:] @ Wy + by
// ---------------------------------------------------------------------------
__global__ __launch_bounds__(1024) void k_prep_yg0(
    const float* __restrict__ Y, const float* __restrict__ Wy,
    const float* __restrict__ by, float* __restrict__ yg0t)
{
  const int t = blockIdx.x, col = threadIdx.x;
  float wv[10];
  #pragma unroll
  for (int i = 0; i < 10; ++i) wv[i] = Wy[i * 1024 + col];
  const float bv = by[col];
  for (int b = 0; b < 32; ++b) {
    float a = bv;
    #pragma unroll
    for (int i = 0; i < 10; ++i) a += Y[((size_t)b * 64 + t) * 10 + i] * wv[i];
    yg0t[((size_t)t * 1024 + col) * 32 + b] = a;
  }
}

// ---------------------------------------------------------------------------
// k_scan: barrier-free streaming LSTM scan. One block per LSTM (65 blocks,
// 512 thr = 8 waves). Wave w owns states [w*32, w*32+32) x all 4 gates.
// U is STREAMED from L2 in fragment order every step (512 KB/step/block,
// 1-deep prefetch); h lives block-local in LDS frag layout (f16).
// No cross-block sync; feature-mean via fire-and-forget atomicAdd.
// ---------------------------------------------------------------------------
__global__ __launch_bounds__(512, 2) void k_scan(
    const float* __restrict__ Xt,
    const float* __restrict__ Wxp, const float* __restrict__ bxp,
    const float* __restrict__ Wxn, const float* __restrict__ bxn,
    const f16* __restrict__ Uf2, const float* __restrict__ yg0t,
    float* __restrict__ Yh, float* __restrict__ Ph, float* __restrict__ Nh)
{
  __shared__ __align__(16) f16 hfrag[2 * 8 * 64 * 8];  // [mt][kt][lane][e], 16 KB
  const int tid = threadIdx.x;
  const int w = tid >> 6, l = tid & 63;
  const int cl = l & 15, lq = l >> 4;
  const int lstm = blockIdx.x;
  const bool isY = (lstm == 64);
  const int s = (lstm >= 32 && !isY) ? 1 : 0;
  const int f = lstm & 31;

  const f16* UB = Uf2 + ((size_t)(lstm * 8 + w) * 64) * 512 + (size_t)l * 8;

  float Wc[4][2], Bc[4][2];
  const float* xrow = nullptr;
  if (!isY) {
    const float* Wf = (s ? Wxn : Wxp) + (size_t)f * 1024;
    const float* bf = (s ? bxn : bxp) + (size_t)f * 1024;
    #pragma unroll
    for (int g = 0; g < 4; ++g)
      #pragma unroll
      for (int nt = 0; nt < 2; ++nt) {
        const int col = g * 256 + w * 32 + nt * 16 + cl;
        Wc[g][nt] = Wf[col]; Bc[g][nt] = bf[col];
      }
    xrow = Xt + (size_t)(s * 32 + f) * 2048;
  }
  float* Acc = s ? Nh : Ph;

  float c[2][2][4];  // [nt][mt][j]
  #pragma unroll
  for (int nt = 0; nt < 2; ++nt)
    #pragma unroll
    for (int mt = 0; mt < 2; ++mt)
      #pragma unroll
      for (int j = 0; j < 4; ++j) c[nt][mt][j] = 0.f;

  for (int i = tid; i < 1024; i += 512) ((uint4*)hfrag)[i] = uint4{0, 0, 0, 0};
  __syncthreads();

  for (int t = 0; t < T; ++t) {
    f16x8 Uc[8], Un[8];
    #pragma unroll
    for (int ct = 0; ct < 8; ++ct) Uc[ct] = *(const f16x8*)(UB + ct * 512);

    f32x4 acc[8][2];
    #pragma unroll
    for (int ct = 0; ct < 8; ++ct) { acc[ct][0] = f32x4{0,0,0,0}; acc[ct][1] = f32x4{0,0,0,0}; }

    #pragma unroll
    for (int kt = 0; kt < 8; ++kt) {
      if (kt < 7) {
        #pragma unroll
        for (int ct = 0; ct < 8; ++ct)
          Un[ct] = *(const f16x8*)(UB + ((kt + 1) * 8 + ct) * 512);
      }
      const f16x8 a0 = *(const f16x8*)(hfrag + (0 * 8 + kt) * 512 + l * 8);
      const f16x8 a1 = *(const f16x8*)(hfrag + (1 * 8 + kt) * 512 + l * 8);
      #pragma unroll
      for (int ct = 0; ct < 8; ++ct) {
        acc[ct][0] = __builtin_amdgcn_mfma_f32_16x16x32_f16(a0, Uc[ct], acc[ct][0], 0, 0, 0);
        acc[ct][1] = __builtin_amdgcn_mfma_f32_16x16x32_f16(a1, Uc[ct], acc[ct][1], 0, 0, 0);
      }
      #pragma unroll
      for (int ct = 0; ct < 8; ++ct) Uc[ct] = Un[ct];
    }
    __syncthreads();   // all waves done reading hfrag

    #pragma unroll
    for (int mt = 0; mt < 2; ++mt) {
      float4 xq;
      if (!isY) xq = *(const float4*)(xrow + t * 32 + mt * 16 + lq * 4);
      #pragma unroll
      for (int nt = 0; nt < 2; ++nt) {
        float4 yq[4];
        if (isY) {
          #pragma unroll
          for (int g = 0; g < 4; ++g) {
            const int col = g * 256 + w * 32 + nt * 16 + cl;
            yq[g] = *(const float4*)(yg0t + ((size_t)t * 1024 + col) * 32 + mt * 16 + lq * 4);
          }
        }
        const int n = w * 32 + nt * 16 + cl;
        #pragma unroll
        for (int j = 0; j < 4; ++j) {
          const int b = mt * 16 + lq * 4 + j;
          float p0, p1, p2, p3;
          if (isY) {
            p0 = acc[0 * 2 + nt][mt][j] + ((const float*)&yq[0])[j];
            p1 = acc[1 * 2 + nt][mt][j] + ((const float*)&yq[1])[j];
            p2 = acc[2 * 2 + nt][mt][j] + ((const float*)&yq[2])[j];
            p3 = acc[3 * 2 + nt][mt][j] + ((const float*)&yq[3])[j];
          } else {
            const float x = ((const float*)&xq)[j];
            p0 = acc[0 * 2 + nt][mt][j] + x * Wc[0][nt] + Bc[0][nt];
            p1 = acc[1 * 2 + nt][mt][j] + x * Wc[1][nt] + Bc[1][nt];
            p2 = acc[2 * 2 + nt][mt][j] + x * Wc[2][nt] + Bc[2][nt];
            p3 = acc[3 * 2 + nt][mt][j] + x * Wc[3][nt] + Bc[3][nt];
          }
          const float ig = sigm(p0), fg = sigm(p1), gy = ftanh(p2), og = sigm(p3);
          c[nt][mt][j] = fg * c[nt][mt][j] + ig * gy;
          const float h = og * ftanh(c[nt][mt][j]);
          // hfrag write: kt slab = w, lane' = (lq*4+j) + (nt*2 + (cl>>3))*16, e = cl&7
          const int lanep = (lq * 4 + j) + (nt * 2 + (cl >> 3)) * 16;
          hfrag[(mt * 8 + w) * 512 + lanep * 8 + (cl & 7)] = (f16)h;
          if (isY) Yh[((size_t)b * T + t) * H + n] = h;
          else atomicAdd(&Acc[((size_t)b * T + t) * H + n], h * 0.03125f);
        }
      }
    }
    __syncthreads();
  }
}

// ---------------------------------------------------------------------------
// k_xg: MI-LSTM input projections.
// ---------------------------------------------------------------------------
__global__ __launch_bounds__(1024) void k_xg(
    const float* __restrict__ Yh, const float* __restrict__ Ph, const float* __restrict__ Nh,
    const float* __restrict__ Wm, const float* __restrict__ bm,
    const float* __restrict__ Wpa, const float* __restrict__ bpa,
    const float* __restrict__ Wna, const float* __restrict__ bna,
    float* __restrict__ yg, float* __restrict__ pg, float* __restrict__ ng)
{
  __shared__ __align__(16) float A[8][768];
  const int tid = threadIdx.x;
  const int ro  = blockIdx.x * 8;

  for (int idx = tid; idx < 8 * 768; idx += 1024) {
    const int r = idx / 768, cc = idx % 768;
    const int row = ro + r;
    float v;
    if (cc < 256)      v = Yh[(size_t)row * H + cc];
    else if (cc < 512) v = Ph[(size_t)row * H + (cc - 256)];
    else               v = Nh[(size_t)row * H + (cc - 512)];
    A[r][cc] = v;
  }
  __syncthreads();

  float acc[8];
  #pragma unroll
  for (int r = 0; r < 8; ++r) acc[r] = bm[tid];
  for (int k = 0; k < H; k += 4) {
    const float w0 = Wm[(k + 0) * 1024 + tid];
    const float w1 = Wm[(k + 1) * 1024 + tid];
    const float w2 = Wm[(k + 2) * 1024 + tid];
    const float w3 = Wm[(k + 3) * 1024 + tid];
    #pragma unroll
    for (int r = 0; r < 8; ++r) {
      const float4 av = *(const float4*)&A[r][k];
      acc[r] += w0 * av.x + w1 * av.y + w2 * av.z + w3 * av.w;
    }
  }
  #pragma unroll
  for (int r = 0; r < 8; ++r) yg[(size_t)(ro + r) * 1024 + tid] = acc[r];

  const int col = tid & 511;
  const float* Wx = (tid < 512) ? Wpa : Wna;
  const float* bx = (tid < 512) ? bpa : bna;
  float* outp     = (tid < 512) ? pg : ng;
  const int aoff  = (tid < 512) ? 256 : 512;
  #pragma unroll
  for (int r = 0; r < 8; ++r) acc[r] = bx[col];
  for (int k = 0; k < H; k += 4) {
    const float w0 = Wx[(k + 0) * 512 + col];
    const float w1 = Wx[(k + 1) * 512 + col];
    const float w2 = Wx[(k + 2) * 512 + col];
    const float w3 = Wx[(k + 3) * 512 + col];
    #pragma unroll
    for (int r = 0; r < 8; ++r) {
      const float4 av = *(const float4*)&A[r][aoff + k];
      acc[r] += w0 * av.x + w1 * av.y + w2 * av.z + w3 * av.w;
    }
  }
  #pragma unroll
  for (int r = 0; r < 8; ++r) outp[(size_t)(ro + r) * 512 + col] = acc[r];
}

// ---------------------------------------------------------------------------
// k_mi: cooperative MI-LSTM, 16 real blocks co-located on ONE XCD via the
// dummy-block trick (grid 121, only blockIdx%8==0 works -> all on XCD 0
// under round-robin dispatch). Barriers + Hh/Hc/Spart exchanges stay L2-local.
// ---------------------------------------------------------------------------
__global__ __launch_bounds__(576) void k_mi(
    const float* __restrict__ yg, const float* __restrict__ pg, const float* __restrict__ ng,
    const f16* __restrict__ Ufmi, const float* __restrict__ ba,
    f16* __restrict__ Hh, f16* __restrict__ Hc, float* __restrict__ Spart,
    unsigned* __restrict__ bar, float* __restrict__ Hm)
{
  if (blockIdx.x & 7) return;            // dummy block (XCD co-location)
  __shared__ float g_lds[9][32][16];
  const int tid = threadIdx.x;
  const int w = tid >> 6, l = tid & 63;
  const int cl = l & 15, lq = l >> 4;
  const int blk = blockIdx.x >> 3;       // 0..15

  f16x8 U[8];
  #pragma unroll
  for (int kt = 0; kt < 8; ++kt)
    U[kt] = *(const f16x8*)(Ufmi + (((size_t)blk * 9 + w) * 8 + kt) * 512 + (size_t)l * 8);

  const int b2 = tid >> 4, nl = tid & 15;
  const int n2 = blk * 16 + nl;
  const float bav = ba[n2];
  float creg = 0.f;
  unsigned cnt = 0;

  for (int t = 0; t < T; ++t) {
    float pre[8];
    if (tid < 512) {
      const size_t row = (size_t)b2 * T + t;
      #pragma unroll
      for (int g = 0; g < 4; ++g) pre[g] = yg[row * 1024 + g * 256 + n2];
      pre[4] = pg[row * 512 + n2];       pre[5] = pg[row * 512 + 256 + n2];
      pre[6] = ng[row * 512 + n2];       pre[7] = ng[row * 512 + 256 + n2];
    }
    const f16* asrc = (w == 8) ? Hc : Hh;
    f32x4 acc[2] = {f32x4{0,0,0,0}, f32x4{0,0,0,0}};
    #pragma unroll
    for (int mt = 0; mt < 2; ++mt) {
      f16x8 a8[8];
      #pragma unroll
      for (int kt = 0; kt < 8; ++kt)
        a8[kt] = *(const f16x8*)(asrc + (16 * mt + cl) * 256 + kt * 32 + lq * 8);
      #pragma unroll
      for (int kt = 0; kt < 8; ++kt)
        acc[mt] = __builtin_amdgcn_mfma_f32_16x16x32_f16(a8[kt], U[kt], acc[mt], 0, 0, 0);
    }
    #pragma unroll
    for (int mt = 0; mt < 2; ++mt)
      #pragma unroll
      for (int j = 0; j < 4; ++j)
        g_lds[w][lq * 4 + j + 16 * mt][cl] = acc[mt][j];
    __syncthreads();

    float l0 = 0.f, l1 = 0.f, l2 = 0.f, fg = 0.f, og = 0.f;
    if (tid < 512) {
      const float gi = sigm(g_lds[0][b2][nl] + pre[0]);
      fg             = sigm(g_lds[1][b2][nl] + pre[1]);
      const float gy = ftanh(g_lds[2][b2][nl] + pre[2]);
      og             = sigm(g_lds[3][b2][nl] + pre[3]);
      const float ip = sigm(g_lds[4][b2][nl] + pre[4]);
      const float cp = ftanh(g_lds[5][b2][nl] + pre[5]);
      const float in = sigm(g_lds[6][b2][nl] + pre[6]);
      const float cn = ftanh(g_lds[7][b2][nl] + pre[7]);
      const float att = ftanh(g_lds[8][b2][nl] + bav);
      l0 = gi * gy; l1 = ip * cp; l2 = in * cn;
      float v0 = l0 * att, v1 = l1 * att, v2 = l2 * att;
      #pragma unroll
      for (int off = 1; off < 16; off <<= 1) {
        v0 += __shfl_xor(v0, off);
        v1 += __shfl_xor(v1, off);
        v2 += __shfl_xor(v2, off);
      }
      if (nl == 0) {
        float* sp = Spart + ((size_t)t * 32 + b2) * 48 + blk;
        sp[0] = v0; sp[16] = v1; sp[32] = v2;
      }
    }
    ++cnt; gridbar(bar, 16u * cnt);
    if (tid < 512) {
      float sv = 0.f;
      if (nl < 3) {
        const float* sp = Spart + ((size_t)t * 32 + b2) * 48 + nl * 16;
        #pragma unroll
        for (int q = 0; q < 16; ++q) sv += sp[q];
      }
      const int base = l & 0x30;
      const float s0 = __shfl(sv, base | 0);
      const float s1 = __shfl(sv, base | 1);
      const float s2 = __shfl(sv, base | 2);
      const float m = fmaxf(s0, fmaxf(s1, s2));
      const float e0 = __expf(s0 - m), e1 = __expf(s1 - m), e2 = __expf(s2 - m);
      const float lt = (e0 * l0 + e1 * l1 + e2 * l2) / (e0 + e1 + e2);
      creg = fg * creg + lt;
      const float h = og * ftanh(creg);
      Hh[b2 * 256 + n2] = (f16)h;
      Hc[b2 * 256 + n2] = (f16)creg;
      Hm[((size_t)b2 * T + t) * H + n2] = h;
    }
    if (t < T - 1) { ++cnt; gridbar(bar, 16u * cnt); }
  }
}

// ---------------------------------------------------------------------------
// k_att: temporal additive attention + linear head.
// ---------------------------------------------------------------------------
__global__ __launch_bounds__(256) void k_att(
    const float* __restrict__ Hm, const float* __restrict__ Watt, const float* __restrict__ batt,
    const float* __restrict__ vatt, const float* __restrict__ Wlin, const float* __restrict__ blin,
    float* __restrict__ out)
{
  __shared__ __align__(16) float hm8[8][H];
  __shared__ float vred[8][4];
  __shared__ float s_lds[T];
  __shared__ float alpha_lds[T];
  __shared__ float red4[4];
  const int n = threadIdx.x;
  const int b = blockIdx.x;
  const float bn = batt[n], vn = vatt[n];

  for (int t0 = 0; t0 < T; t0 += 8) {
    __syncthreads();
    #pragma unroll
    for (int r = 0; r < 8; ++r) hm8[r][n] = Hm[((size_t)b * T + t0 + r) * H + n];
    __syncthreads();
    float acc[8];
    #pragma unroll
    for (int r = 0; r < 8; ++r) acc[r] = bn;
    for (int k = 0; k < H; k += 4) {
      const float w0 = Watt[(k + 0) * H + n];
      const float w1 = Watt[(k + 1) * H + n];
      const float w2 = Watt[(k + 2) * H + n];
      const float w3 = Watt[(k + 3) * H + n];
      #pragma unroll
      for (int r = 0; r < 8; ++r) {
        const float4 hv = *(const float4*)&hm8[r][k];
        acc[r] += w0 * hv.x + w1 * hv.y + w2 * hv.z + w3 * hv.w;
      }
    }
    #pragma unroll
    for (int r = 0; r < 8; ++r) {
      float v = tanhf(acc[r]) * vn;
      for (int off = 32; off; off >>= 1) v += __shfl_down(v, off);
      if ((n & 63) == 0) vred[r][n >> 6] = v;
    }
    __syncthreads();
    if (n < 8) s_lds[t0 + n] = vred[n][0] + vred[n][1] + vred[n][2] + vred[n][3];
  }
  __syncthreads();

  if (n < T) {
    const float sv = s_lds[n];
    float m = sv;
    for (int off = 32; off; off >>= 1) m = fmaxf(m, __shfl_xor(m, off));
    const float e = expf(sv - m);
    float sum = e;
    for (int off = 32; off; off >>= 1) sum += __shfl_xor(sum, off);
    alpha_lds[n] = e / sum;
  }
  __syncthreads();

  float acc = 0.f;
  for (int t = 0; t < T; ++t) acc += alpha_lds[t] * Hm[((size_t)b * T + t) * H + n];
  float p = acc * Wlin[n];
  for (int off = 32; off; off >>= 1) p += __shfl_down(p, off);
  if ((n & 63) == 0) red4[n >> 6] = p;
  __syncthreads();
  if (n == 0) out[b] = fmaxf(red4[0] + red4[1] + red4[2] + red4[3] + blin[0], 0.f);
}

// ---------------------------------------------------------------------------
extern "C" void kernel_launch(void* const* d_in, const int* in_sizes, int n_in,
                              void* d_out, int out_size, void* d_ws, size_t ws_size,
                              hipStream_t stream) {
  const float* Yin  = (const float*)d_in[0];
  const float* Xp   = (const float*)d_in[1];
  const float* Xn   = (const float*)d_in[2];
  const float* Wy   = (const float*)d_in[3];
  const float* Uy   = (const float*)d_in[4];
  const float* by   = (const float*)d_in[5];
  const float* Wxp  = (const float*)d_in[6];
  const float* Uxp  = (const float*)d_in[7];
  const float* bxp  = (const float*)d_in[8];
  const float* Wxn  = (const float*)d_in[9];
  const float* Uxn  = (const float*)d_in[10];
  const float* bxn  = (const float*)d_in[11];
  const float* Wm   = (const float*)d_in[12];
  const float* Um   = (const float*)d_in[13];
  const float* bm   = (const float*)d_in[14];
  const float* Wpa  = (const float*)d_in[15];
  const float* Upa  = (const float*)d_in[16];
  const float* bpa  = (const float*)d_in[17];
  const float* Wna  = (const float*)d_in[18];
  const float* Una  = (const float*)d_in[19];
  const float* bna  = (const float*)d_in[20];
  const float* Wa   = (const float*)d_in[21];
  const float* ba   = (const float*)d_in[22];
  const float* Watt = (const float*)d_in[23];
  const float* batt = (const float*)d_in[24];
  const float* vatt = (const float*)d_in[25];
  const float* Wlin = (const float*)d_in[26];
  const float* blin = (const float*)d_in[27];

  float* ws = (float*)d_ws;
  float*    Yh    = ws;                         // 524288
  float*    Ph    = ws + 524288;                // 524288
  float*    Nh    = ws + 1048576;               // 524288
  float*    Hm    = ws + 1572864;               // 524288
  float*    yg    = ws + 2097152;               // 2097152
  float*    pg    = ws + 4194304;               // 1048576
  float*    ng    = ws + 5242880;               // 1048576
  float*    yg0t  = ws + 6291456;               // 2097152
  float*    Xt    = ws + 8388608;               // 131072
  f16*      Uf2   = (f16*)(ws + 8519680);       // 17039360 f16 (8519680 floats)
  f16*      Ufmi  = (f16*)(ws + 17039360);      // 589824 f16 (294912 floats)
  f16*      Hh    = (f16*)(ws + 17334272);      // 8192 f16
  f16*      Hc    = (f16*)(ws + 17338368);      // 8192 f16
  float*    Spart = ws + 17342464;              // 98304
  unsigned* bars  = (unsigned*)(ws + 17440768); // 64 u32
  float*    out   = (float*)d_out;

  hipMemsetAsync(Ph, 0, (size_t)2 * 524288 * sizeof(float), stream);   // Ph+Nh
  hipMemsetAsync(Hh, 0, (size_t)2 * 8192 * sizeof(f16), stream);       // Hh+Hc
  hipMemsetAsync(bars, 0, (size_t)64 * sizeof(unsigned), stream);

  k_prep_u   <<<520, 256, 0, stream>>>(Uxp, Uxn, Uy, Uf2);
  k_prep_umi <<<144, 512, 0, stream>>>(Um, Upa, Una, Wa, Ufmi);
  k_prep_x   <<<64, 512, 0, stream>>>(Xp, Xn, Xt);
  k_prep_yg0 <<<64, 1024, 0, stream>>>(Yin, Wy, by, yg0t);

  k_scan<<<65, 512, 0, stream>>>(Xt, Wxp, bxp, Wxn, bxn, Uf2, yg0t, Yh, Ph, Nh);
  k_xg  <<<256, 1024, 0, stream>>>(Yh, Ph, Nh, Wm, bm, Wpa, bpa, Wna, bna, yg, pg, ng);
  k_mi  <<<121, 576, 0, stream>>>(yg, pg, ng, Ufmi, ba, Hh, Hc, Spart, bars, Hm);
  k_att <<<32, 256, 0, stream>>>(Hm, Watt, batt, vatt, Wlin, blin, out);
}

// Round 5
// 2331.931 us; speedup vs baseline: 2.2587x; 2.2587x over previous
//
#include <hip/hip_runtime.h>
#include <math.h>

#define T 64
#define H 256

typedef _Float16 f16;
typedef _Float16 f16x8 __attribute__((ext_vector_type(8)));
typedef float f32x4 __attribute__((ext_vector_type(4)));

__device__ __forceinline__ float sigm(float x) { return 1.f / (1.f + __expf(-x)); }
__device__ __forceinline__ float ftanh(float x) { return 1.f - 2.f / (__expf(2.f * x) + 1.f); }

// ---------------------------------------------------------------------------
// k_prep_u: coalesced frag-ordering of the 65 scan-LSTM U matrices into f16.
//   Uf2 flat idx = ((((lstm*8 + w)*8 + kt)*8 + ct)*64 + l)*8 + e
//   = U[k = kt*32 + (l>>4)*8 + e][col = g*256 + w*32 + nt*16 + (l&15)]
//   with g = ct>>1, nt = ct&1.
// ---------------------------------------------------------------------------
__global__ __launch_bounds__(256) void k_prep_u(
    const float* __restrict__ Uxp, const float* __restrict__ Uxn,
    const float* __restrict__ Uy, f16* __restrict__ Uf2)
{
  __shared__ f16 lds[32][1024];  // 64 KB
  const int tid = threadIdx.x;
  const int lstm = blockIdx.x >> 3, kt = blockIdx.x & 7;
  const float* src = (lstm < 32) ? (Uxp + (size_t)lstm * 262144)
                   : (lstm < 64) ? (Uxn + (size_t)(lstm - 32) * 262144)
                   : Uy;
  const int k0 = kt * 32;
  for (int i = tid; i < 32 * 1024; i += 256) {
    const int row = i >> 10, col = i & 1023;
    lds[row][col] = (f16)src[(size_t)(k0 + row) * 1024 + col];
  }
  __syncthreads();
  const int l = tid & 63, c0 = tid >> 6;
  for (int c = c0; c < 64; c += 4) {
    const int w = c >> 3, ct = c & 7, g = ct >> 1, nt = ct & 1;
    f16x8 v;
    #pragma unroll
    for (int e = 0; e < 8; ++e)
      v[e] = lds[(l >> 4) * 8 + e][g * 256 + w * 32 + nt * 16 + (l & 15)];
    *(f16x8*)(Uf2 + (((((size_t)lstm * 8 + w) * 8 + kt) * 8 + ct) * 64 + l) * 8) = v;
  }
}

// ---------------------------------------------------------------------------
// k_prep_wmi: pack all MI-LSTM recurrent weights into one f16 buffer for the
// streaming k_mi. Column space c in [0,2304): 0-1023 Um (gate g = c>>8),
// 1024-1535 Upa, 1536-2047 Una, 2048-2303 Wa.
// Layout: Wmi[((kc*2304) + c)*8 + e] = W[k = kc*8+e][scol]  (f16)
// Grid 1152 x 64: lane l -> col c0 + (l>>5), kc = l&31.
// ---------------------------------------------------------------------------
__global__ __launch_bounds__(64) void k_prep_wmi(
    const float* __restrict__ Um, const float* __restrict__ Upa,
    const float* __restrict__ Una, const float* __restrict__ Wa,
    f16* __restrict__ Wmi)
{
  const int l = threadIdx.x;
  const int c = blockIdx.x * 2 + (l >> 5);
  const int kc = l & 31;
  const float* src; int scol, ld;
  if (c < 1024)      { src = Um;  scol = c;        ld = 1024; }
  else if (c < 1536) { src = Upa; scol = c - 1024; ld = 512;  }
  else if (c < 2048) { src = Una; scol = c - 1536; ld = 512;  }
  else               { src = Wa;  scol = c - 2048; ld = 256;  }
  f16x8 v;
  #pragma unroll
  for (int e = 0; e < 8; ++e) v[e] = (f16)src[(size_t)(kc * 8 + e) * ld + scol];
  *(f16x8*)(Wmi + ((size_t)kc * 2304 + c) * 8) = v;
}

// ---------------------------------------------------------------------------
// k_prep_x: X[b][t][f] -> Xt[s][f][t][b]
// ---------------------------------------------------------------------------
__global__ __launch_bounds__(512) void k_prep_x(
    const float* __restrict__ Xp, const float* __restrict__ Xn, float* __restrict__ Xt)
{
  const int s = blockIdx.x >> 5, f = blockIdx.x & 31;
  const float* X = s ? Xn : Xp;
  for (int i = threadIdx.x; i < 2048; i += 512) {
    const int t = i >> 5, b = i & 31;
    Xt[((size_t)(s * 32 + f) * 64 + t) * 32 + b] = X[((size_t)b * 64 + t) * 32 + f];
  }
}

// ---------------------------------------------------------------------------
// k_prep_yg0: yg0t[t][col][b] = Y[b,t,:] @ Wy + by
// ---------------------------------------------------------------------------
__global__ __launch_bounds__(1024) void k_prep_yg0(
    const float* __restrict__ Y, const float* __restrict__ Wy,
    const float* __restrict__ by, float* __restrict__ yg0t)
{
  const int t = blockIdx.x, col = threadIdx.x;
  float wv[10];
  #pragma unroll
  for (int i = 0; i < 10; ++i) wv[i] = Wy[i * 1024 + col];
  const float bv = by[col];
  for (int b = 0; b < 32; ++b) {
    float a = bv;
    #pragma unroll
    for (int i = 0; i < 10; ++i) a += Y[((size_t)b * 64 + t) * 10 + i] * wv[i];
    yg0t[((size_t)t * 1024 + col) * 32 + b] = a;
  }
}

// ---------------------------------------------------------------------------
// k_scan: barrier-free streaming LSTM scan (unchanged from round 4).
// One block per LSTM (65 blocks, 512 thr = 8 waves); U streamed from L2 in
// fragment order every step; h block-local in LDS frag layout (f16).
// ---------------------------------------------------------------------------
__global__ __launch_bounds__(512, 2) void k_scan(
    const float* __restrict__ Xt,
    const float* __restrict__ Wxp, const float* __restrict__ bxp,
    const float* __restrict__ Wxn, const float* __restrict__ bxn,
    const f16* __restrict__ Uf2, const float* __restrict__ yg0t,
    float* __restrict__ Yh, float* __restrict__ Ph, float* __restrict__ Nh)
{
  __shared__ __align__(16) f16 hfrag[2 * 8 * 64 * 8];  // [mt][kt][lane][e], 16 KB
  const int tid = threadIdx.x;
  const int w = tid >> 6, l = tid & 63;
  const int cl = l & 15, lq = l >> 4;
  const int lstm = blockIdx.x;
  const bool isY = (lstm == 64);
  const int s = (lstm >= 32 && !isY) ? 1 : 0;
  const int f = lstm & 31;

  const f16* UB = Uf2 + ((size_t)(lstm * 8 + w) * 64) * 512 + (size_t)l * 8;

  float Wc[4][2], Bc[4][2];
  const float* xrow = nullptr;
  if (!isY) {
    const float* Wf = (s ? Wxn : Wxp) + (size_t)f * 1024;
    const float* bf = (s ? bxn : bxp) + (size_t)f * 1024;
    #pragma unroll
    for (int g = 0; g < 4; ++g)
      #pragma unroll
      for (int nt = 0; nt < 2; ++nt) {
        const int col = g * 256 + w * 32 + nt * 16 + cl;
        Wc[g][nt] = Wf[col]; Bc[g][nt] = bf[col];
      }
    xrow = Xt + (size_t)(s * 32 + f) * 2048;
  }
  float* Acc = s ? Nh : Ph;

  float c[2][2][4];  // [nt][mt][j]
  #pragma unroll
  for (int nt = 0; nt < 2; ++nt)
    #pragma unroll
    for (int mt = 0; mt < 2; ++mt)
      #pragma unroll
      for (int j = 0; j < 4; ++j) c[nt][mt][j] = 0.f;

  for (int i = tid; i < 1024; i += 512) ((uint4*)hfrag)[i] = uint4{0, 0, 0, 0};
  __syncthreads();

  for (int t = 0; t < T; ++t) {
    f16x8 Uc[8], Un[8];
    #pragma unroll
    for (int ct = 0; ct < 8; ++ct) Uc[ct] = *(const f16x8*)(UB + ct * 512);

    f32x4 acc[8][2];
    #pragma unroll
    for (int ct = 0; ct < 8; ++ct) { acc[ct][0] = f32x4{0,0,0,0}; acc[ct][1] = f32x4{0,0,0,0}; }

    #pragma unroll
    for (int kt = 0; kt < 8; ++kt) {
      if (kt < 7) {
        #pragma unroll
        for (int ct = 0; ct < 8; ++ct)
          Un[ct] = *(const f16x8*)(UB + ((kt + 1) * 8 + ct) * 512);
      }
      const f16x8 a0 = *(const f16x8*)(hfrag + (0 * 8 + kt) * 512 + l * 8);
      const f16x8 a1 = *(const f16x8*)(hfrag + (1 * 8 + kt) * 512 + l * 8);
      #pragma unroll
      for (int ct = 0; ct < 8; ++ct) {
        acc[ct][0] = __builtin_amdgcn_mfma_f32_16x16x32_f16(a0, Uc[ct], acc[ct][0], 0, 0, 0);
        acc[ct][1] = __builtin_amdgcn_mfma_f32_16x16x32_f16(a1, Uc[ct], acc[ct][1], 0, 0, 0);
      }
      #pragma unroll
      for (int ct = 0; ct < 8; ++ct) Uc[ct] = Un[ct];
    }
    __syncthreads();   // all waves done reading hfrag

    #pragma unroll
    for (int mt = 0; mt < 2; ++mt) {
      float4 xq;
      if (!isY) xq = *(const float4*)(xrow + t * 32 + mt * 16 + lq * 4);
      #pragma unroll
      for (int nt = 0; nt < 2; ++nt) {
        float4 yq[4];
        if (isY) {
          #pragma unroll
          for (int g = 0; g < 4; ++g) {
            const int col = g * 256 + w * 32 + nt * 16 + cl;
            yq[g] = *(const float4*)(yg0t + ((size_t)t * 1024 + col) * 32 + mt * 16 + lq * 4);
          }
        }
        const int n = w * 32 + nt * 16 + cl;
        #pragma unroll
        for (int j = 0; j < 4; ++j) {
          const int b = mt * 16 + lq * 4 + j;
          float p0, p1, p2, p3;
          if (isY) {
            p0 = acc[0 * 2 + nt][mt][j] + ((const float*)&yq[0])[j];
            p1 = acc[1 * 2 + nt][mt][j] + ((const float*)&yq[1])[j];
            p2 = acc[2 * 2 + nt][mt][j] + ((const float*)&yq[2])[j];
            p3 = acc[3 * 2 + nt][mt][j] + ((const float*)&yq[3])[j];
          } else {
            const float x = ((const float*)&xq)[j];
            p0 = acc[0 * 2 + nt][mt][j] + x * Wc[0][nt] + Bc[0][nt];
            p1 = acc[1 * 2 + nt][mt][j] + x * Wc[1][nt] + Bc[1][nt];
            p2 = acc[2 * 2 + nt][mt][j] + x * Wc[2][nt] + Bc[2][nt];
            p3 = acc[3 * 2 + nt][mt][j] + x * Wc[3][nt] + Bc[3][nt];
          }
          const float ig = sigm(p0), fg = sigm(p1), gy = ftanh(p2), og = sigm(p3);
          c[nt][mt][j] = fg * c[nt][mt][j] + ig * gy;
          const float h = og * ftanh(c[nt][mt][j]);
          const int lanep = (lq * 4 + j) + (nt * 2 + (cl >> 3)) * 16;
          hfrag[(mt * 8 + w) * 512 + lanep * 8 + (cl & 7)] = (f16)h;
          if (isY) Yh[((size_t)b * T + t) * H + n] = h;
          else atomicAdd(&Acc[((size_t)b * T + t) * H + n], h * 0.03125f);
        }
      }
    }
    __syncthreads();
  }
}

// ---------------------------------------------------------------------------
// k_xg: MI-LSTM input projections.
// ---------------------------------------------------------------------------
__global__ __launch_bounds__(1024) void k_xg(
    const float* __restrict__ Yh, const float* __restrict__ Ph, const float* __restrict__ Nh,
    const float* __restrict__ Wm, const float* __restrict__ bm,
    const float* __restrict__ Wpa, const float* __restrict__ bpa,
    const float* __restrict__ Wna, const float* __restrict__ bna,
    float* __restrict__ yg, float* __restrict__ pg, float* __restrict__ ng)
{
  __shared__ __align__(16) float A[8][768];
  const int tid = threadIdx.x;
  const int ro  = blockIdx.x * 8;

  for (int idx = tid; idx < 8 * 768; idx += 1024) {
    const int r = idx / 768, cc = idx % 768;
    const int row = ro + r;
    float v;
    if (cc < 256)      v = Yh[(size_t)row * H + cc];
    else if (cc < 512) v = Ph[(size_t)row * H + (cc - 256)];
    else               v = Nh[(size_t)row * H + (cc - 512)];
    A[r][cc] = v;
  }
  __syncthreads();

  float acc[8];
  #pragma unroll
  for (int r = 0; r < 8; ++r) acc[r] = bm[tid];
  for (int k = 0; k < H; k += 4) {
    const float w0 = Wm[(k + 0) * 1024 + tid];
    const float w1 = Wm[(k + 1) * 1024 + tid];
    const float w2 = Wm[(k + 2) * 1024 + tid];
    const float w3 = Wm[(k + 3) * 1024 + tid];
    #pragma unroll
    for (int r = 0; r < 8; ++r) {
      const float4 av = *(const float4*)&A[r][k];
      acc[r] += w0 * av.x + w1 * av.y + w2 * av.z + w3 * av.w;
    }
  }
  #pragma unroll
  for (int r = 0; r < 8; ++r) yg[(size_t)(ro + r) * 1024 + tid] = acc[r];

  const int col = tid & 511;
  const float* Wx = (tid < 512) ? Wpa : Wna;
  const float* bx = (tid < 512) ? bpa : bna;
  float* outp     = (tid < 512) ? pg : ng;
  const int aoff  = (tid < 512) ? 256 : 512;
  #pragma unroll
  for (int r = 0; r < 8; ++r) acc[r] = bx[col];
  for (int k = 0; k < H; k += 4) {
    const float w0 = Wx[(k + 0) * 512 + col];
    const float w1 = Wx[(k + 1) * 512 + col];
    const float w2 = Wx[(k + 2) * 512 + col];
    const float w3 = Wx[(k + 3) * 512 + col];
    #pragma unroll
    for (int r = 0; r < 8; ++r) {
      const float4 av = *(const float4*)&A[r][aoff + k];
      acc[r] += w0 * av.x + w1 * av.y + w2 * av.z + w3 * av.w;
    }
  }
  #pragma unroll
  for (int r = 0; r < 8; ++r) outp[(size_t)(ro + r) * 512 + col] = acc[r];
}

// ---------------------------------------------------------------------------
// k_mi v5: one block per batch (32 blocks, 1024 thr), NO cross-block sync.
// Per step, phase1 streams the packed 1.18 MB f16 weight buffer (coalesced
// 16B/lane chunks, unroll-8 pipelining) and dots against h (c for Wa cols)
// broadcast from LDS as f16 (mixed-precision FMA). Phase2: 256 state threads
// do gates/softmax/state update with an in-block shfl+LDS reduce.
// Per-CU stream floor ~8.7 us/step -> ~600 us.
// ---------------------------------------------------------------------------
__global__ __launch_bounds__(1024, 1) void k_mi(
    const float* __restrict__ yg, const float* __restrict__ pg, const float* __restrict__ ng,
    const f16* __restrict__ Wmi, const float* __restrict__ ba,
    float* __restrict__ Hm)
{
  __shared__ float g_all[2304];
  __shared__ __align__(16) f16 h_lds[256];
  __shared__ __align__(16) f16 c_lds[256];
  __shared__ float red[3][4];
  const int tid = threadIdx.x;
  const int b = blockIdx.x;

  if (tid < 256) { h_lds[tid] = (f16)0.f; c_lds[tid] = (f16)0.f; }
  const float bav = (tid < 256) ? ba[tid] : 0.f;
  float creg = 0.f;
  __syncthreads();

  for (int t = 0; t < T; ++t) {
    const size_t row = (size_t)b * T + t;

    // input pre-activations (independent of h; issue early, covered by phase1)
    float pre[8];
    if (tid < 256) {
      #pragma unroll
      for (int g = 0; g < 4; ++g) pre[g] = yg[row * 1024 + g * 256 + tid];
      pre[4] = pg[row * 512 + tid];       pre[5] = pg[row * 512 + 256 + tid];
      pre[6] = ng[row * 512 + tid];       pre[7] = ng[row * 512 + 256 + tid];
    }

    // phase1: streamed recurrent matvec
    for (int c = tid; c < 2304; c += 1024) {
      const f16* hsrc = (c >= 2048) ? c_lds : h_lds;
      const f16* wcol = Wmi + (size_t)c * 8;
      float acc = 0.f;
      #pragma unroll 8
      for (int kc = 0; kc < 32; ++kc) {
        const f16x8 wv = *(const f16x8*)(wcol + (size_t)kc * 2304 * 8);
        const f16x8 hv = *(const f16x8*)(hsrc + kc * 8);
        #pragma unroll
        for (int e = 0; e < 8; ++e) acc += (float)wv[e] * (float)hv[e];
      }
      g_all[c] = acc;
    }
    __syncthreads();

    // phase2: gates, cell-attention softmax, state update
    float l0 = 0.f, l1 = 0.f, l2 = 0.f, fg = 0.f, og = 0.f;
    if (tid < 256) {
      const int n = tid;
      const float gi = sigm(g_all[n]            + pre[0]);
      fg             = sigm(g_all[256 + n]      + pre[1]);
      const float gy = ftanh(g_all[512 + n]     + pre[2]);
      og             = sigm(g_all[768 + n]      + pre[3]);
      const float ip = sigm(g_all[1024 + n]     + pre[4]);
      const float cp = ftanh(g_all[1280 + n]    + pre[5]);
      const float in = sigm(g_all[1536 + n]     + pre[6]);
      const float cn = ftanh(g_all[1792 + n]    + pre[7]);
      const float att = ftanh(g_all[2048 + n]   + bav);
      l0 = gi * gy; l1 = ip * cp; l2 = in * cn;
      float v0 = l0 * att, v1 = l1 * att, v2 = l2 * att;
      #pragma unroll
      for (int off = 32; off; off >>= 1) {
        v0 += __shfl_down(v0, off);
        v1 += __shfl_down(v1, off);
        v2 += __shfl_down(v2, off);
      }
      if ((tid & 63) == 0) {
        red[0][tid >> 6] = v0; red[1][tid >> 6] = v1; red[2][tid >> 6] = v2;
      }
    }
    __syncthreads();

    if (tid < 256) {
      const int n = tid;
      const float s0 = red[0][0] + red[0][1] + red[0][2] + red[0][3];
      const float s1 = red[1][0] + red[1][1] + red[1][2] + red[1][3];
      const float s2 = red[2][0] + red[2][1] + red[2][2] + red[2][3];
      const float m  = fmaxf(s0, fmaxf(s1, s2));
      const float e0 = __expf(s0 - m), e1 = __expf(s1 - m), e2 = __expf(s2 - m);
      const float lt = (e0 * l0 + e1 * l1 + e2 * l2) / (e0 + e1 + e2);
      creg = fg * creg + lt;
      const float h = og * ftanh(creg);
      h_lds[n] = (f16)h;
      c_lds[n] = (f16)creg;
      Hm[row * H + n] = h;
    }
    __syncthreads();
  }
}

// ---------------------------------------------------------------------------
// k_att: temporal additive attention + linear head.
// ---------------------------------------------------------------------------
__global__ __launch_bounds__(256) void k_att(
    const float* __restrict__ Hm, const float* __restrict__ Watt, const float* __restrict__ batt,
    const float* __restrict__ vatt, const float* __restrict__ Wlin, const float* __restrict__ blin,
    float* __restrict__ out)
{
  __shared__ __align__(16) float hm8[8][H];
  __shared__ float vred[8][4];
  __shared__ float s_lds[T];
  __shared__ float alpha_lds[T];
  __shared__ float red4[4];
  const int n = threadIdx.x;
  const int b = blockIdx.x;
  const float bn = batt[n], vn = vatt[n];

  for (int t0 = 0; t0 < T; t0 += 8) {
    __syncthreads();
    #pragma unroll
    for (int r = 0; r < 8; ++r) hm8[r][n] = Hm[((size_t)b * T + t0 + r) * H + n];
    __syncthreads();
    float acc[8];
    #pragma unroll
    for (int r = 0; r < 8; ++r) acc[r] = bn;
    for (int k = 0; k < H; k += 4) {
      const float w0 = Watt[(k + 0) * H + n];
      const float w1 = Watt[(k + 1) * H + n];
      const float w2 = Watt[(k + 2) * H + n];
      const float w3 = Watt[(k + 3) * H + n];
      #pragma unroll
      for (int r = 0; r < 8; ++r) {
        const float4 hv = *(const float4*)&hm8[r][k];
        acc[r] += w0 * hv.x + w1 * hv.y + w2 * hv.z + w3 * hv.w;
      }
    }
    #pragma unroll
    for (int r = 0; r < 8; ++r) {
      float v = tanhf(acc[r]) * vn;
      for (int off = 32; off; off >>= 1) v += __shfl_down(v, off);
      if ((n & 63) == 0) vred[r][n >> 6] = v;
    }
    __syncthreads();
    if (n < 8) s_lds[t0 + n] = vred[n][0] + vred[n][1] + vred[n][2] + vred[n][3];
  }
  __syncthreads();

  if (n < T) {
    const float sv = s_lds[n];
    float m = sv;
    for (int off = 32; off; off >>= 1) m = fmaxf(m, __shfl_xor(m, off));
    const float e = expf(sv - m);
    float sum = e;
    for (int off = 32; off; off >>= 1) sum += __shfl_xor(sum, off);
    alpha_lds[n] = e / sum;
  }
  __syncthreads();

  float acc = 0.f;
  for (int t = 0; t < T; ++t) acc += alpha_lds[t] * Hm[((size_t)b * T + t) * H + n];
  float p = acc * Wlin[n];
  for (int off = 32; off; off >>= 1) p += __shfl_down(p, off);
  if ((n & 63) == 0) red4[n >> 6] = p;
  __syncthreads();
  if (n == 0) out[b] = fmaxf(red4[0] + red4[1] + red4[2] + red4[3] + blin[0], 0.f);
}

// ---------------------------------------------------------------------------
extern "C" void kernel_launch(void* const* d_in, const int* in_sizes, int n_in,
                              void* d_out, int out_size, void* d_ws, size_t ws_size,
                              hipStream_t stream) {
  const float* Yin  = (const float*)d_in[0];
  const float* Xp   = (const float*)d_in[1];
  const float* Xn   = (const float*)d_in[2];
  const float* Wy   = (const float*)d_in[3];
  const float* Uy   = (const float*)d_in[4];
  const float* by   = (const float*)d_in[5];
  const float* Wxp  = (const float*)d_in[6];
  const float* Uxp  = (const float*)d_in[7];
  const float* bxp  = (const float*)d_in[8];
  const float* Wxn  = (const float*)d_in[9];
  const float* Uxn  = (const float*)d_in[10];
  const float* bxn  = (const float*)d_in[11];
  const float* Wm   = (const float*)d_in[12];
  const float* Um   = (const float*)d_in[13];
  const float* bm   = (const float*)d_in[14];
  const float* Wpa  = (const float*)d_in[15];
  const float* Upa  = (const float*)d_in[16];
  const float* bpa  = (const float*)d_in[17];
  const float* Wna  = (const float*)d_in[18];
  const float* Una  = (const float*)d_in[19];
  const float* bna  = (const float*)d_in[20];
  const float* Wa   = (const float*)d_in[21];
  const float* ba   = (const float*)d_in[22];
  const float* Watt = (const float*)d_in[23];
  const float* batt = (const float*)d_in[24];
  const float* vatt = (const float*)d_in[25];
  const float* Wlin = (const float*)d_in[26];
  const float* blin = (const float*)d_in[27];

  float* ws = (float*)d_ws;
  float*    Yh    = ws;                         // 524288
  float*    Ph    = ws + 524288;                // 524288
  float*    Nh    = ws + 1048576;               // 524288
  float*    Hm    = ws + 1572864;               // 524288
  float*    yg    = ws + 2097152;               // 2097152
  float*    pg    = ws + 4194304;               // 1048576
  float*    ng    = ws + 5242880;               // 1048576
  float*    yg0t  = ws + 6291456;               // 2097152
  float*    Xt    = ws + 8388608;               // 131072
  f16*      Uf2   = (f16*)(ws + 8519680);       // 17039360 f16 (8519680 floats)
  f16*      Wmi   = (f16*)(ws + 17039360);      // 589824 f16 (294912 floats)
  float*    out   = (float*)d_out;

  hipMemsetAsync(Ph, 0, (size_t)2 * 524288 * sizeof(float), stream);   // Ph+Nh

  k_prep_u   <<<520, 256, 0, stream>>>(Uxp, Uxn, Uy, Uf2);
  k_prep_wmi <<<1152, 64, 0, stream>>>(Um, Upa, Una, Wa, Wmi);
  k_prep_x   <<<64, 512, 0, stream>>>(Xp, Xn, Xt);
  k_prep_yg0 <<<64, 1024, 0, stream>>>(Yin, Wy, by, yg0t);

  k_scan<<<65, 512, 0, stream>>>(Xt, Wxp, bxp, Wxn, bxn, Uf2, yg0t, Yh, Ph, Nh);
  k_xg  <<<256, 1024, 0, stream>>>(Yh, Ph, Nh, Wm, bm, Wpa, bpa, Wna, bna, yg, pg, ng);
  k_mi  <<<32, 1024, 0, stream>>>(yg, pg, ng, Wmi, ba, Hm);
  k_att <<<32, 256, 0, stream>>>(Hm, Watt, batt, vatt, Wlin, blin, out);
}